// Round 1
// baseline (649.115 us; speedup 1.0000x reference)
//
#include <hip/hip_runtime.h>

#define HBLK 128  // hidden width, fixed by problem

// ---------------- CSR build ----------------
__global__ void zero_counts(int* counts, int n) {
    int i = blockIdx.x * 256 + threadIdx.x;
    if (i < n) counts[i] = 0;
}

__global__ void hist_k(const int* __restrict__ dst, int* counts, int E) {
    int e = blockIdx.x * 256 + threadIdx.x;
    if (e < E) atomicAdd(&counts[dst[e]], 1);
}

// single-block exclusive scan over N counts -> offsets[N+1], cursor copy
__global__ void scan_k(const int* __restrict__ counts, int* offs, int* cursor, int n) {
    __shared__ int lds[256];
    const int t = threadIdx.x;
    const int CH = (n + 255) / 256;
    const int base = t * CH;
    int s = 0;
    for (int i = 0; i < CH; ++i) {
        int idx = base + i;
        if (idx < n) s += counts[idx];
    }
    lds[t] = s;
    __syncthreads();
    for (int off = 1; off < 256; off <<= 1) {
        int add = (t >= off) ? lds[t - off] : 0;
        __syncthreads();
        lds[t] += add;
        __syncthreads();
    }
    int run = lds[t] - s;  // exclusive prefix
    for (int i = 0; i < CH; ++i) {
        int idx = base + i;
        if (idx < n) {
            offs[idx] = run;
            cursor[idx] = run;
            run += counts[idx];
        }
    }
    if (t == 255) offs[n] = lds[255];
}

__global__ void fill_k(const int* __restrict__ dst, const int* __restrict__ src,
                       int* cursor, int* __restrict__ src_sorted, int E) {
    int e = blockIdx.x * 256 + threadIdx.x;
    if (e < E) {
        int p = atomicAdd(&cursor[dst[e]], 1);
        src_sorted[p] = src[e];
    }
}

// ---------------- generic fp32 GEMM: C[M x 128] = A[M x K] @ B[128 x K]^T ----------------
// flags: 1 = accumulate into existing C, 2 = relu at end. bias may be null.
__global__ __launch_bounds__(256) void gemm_nt(
    const float* __restrict__ A, int lda,
    const float* __restrict__ B, int ldb,
    const float* __restrict__ bias,
    float* __restrict__ C,
    int M, int K, int flags)
{
    __shared__ float As[32][36];    // k-major, padded (36*4=144B, 16B aligned rows)
    __shared__ float Bs[32][132];   // k-major, padded (132*4=528B, 16B aligned rows)
    const int tid = threadIdx.x;
    const int row0 = blockIdx.x * 32;
    const int tx = tid & 31;   // col group: cols tx*4 .. tx*4+3
    const int ty = tid >> 5;   // row group: rows ty*4 .. ty*4+3
    float acc[4][4] = {};

    for (int kb = 0; kb < K; kb += 32) {
#pragma unroll
        for (int j = 0; j < 4; ++j) {
            int idx = tid + 256 * j;      // 1024 elems: 32 rows x 32 k
            int r = idx >> 5, k = idx & 31;
            int gr = row0 + r, gk = kb + k;
            As[k][r] = (gr < M && gk < K) ? A[(long)gr * lda + gk] : 0.f;
        }
#pragma unroll
        for (int j = 0; j < 16; ++j) {
            int idx = tid + 256 * j;      // 4096 elems: 128 cols x 32 k
            int c = idx >> 5, k = idx & 31;
            int gk = kb + k;
            Bs[k][c] = (gk < K) ? B[c * ldb + gk] : 0.f;
        }
        __syncthreads();
#pragma unroll
        for (int kk = 0; kk < 32; ++kk) {
            const float4 av = *(const float4*)&As[kk][ty * 4];
            const float4 bv = *(const float4*)&Bs[kk][tx * 4];
            const float aa[4] = {av.x, av.y, av.z, av.w};
            const float bb[4] = {bv.x, bv.y, bv.z, bv.w};
#pragma unroll
            for (int i = 0; i < 4; ++i)
#pragma unroll
                for (int j = 0; j < 4; ++j)
                    acc[i][j] += aa[i] * bb[j];
        }
        __syncthreads();
    }

#pragma unroll
    for (int i = 0; i < 4; ++i) {
        int gr = row0 + ty * 4 + i;
        if (gr >= M) continue;
#pragma unroll
        for (int j = 0; j < 4; ++j) {
            int gc = tx * 4 + j;
            float v = acc[i][j];
            if (bias) v += bias[gc];
            if (flags & 1) v += C[gr * HBLK + gc];
            if (flags & 2) v = fmaxf(v, 0.f);
            C[gr * HBLK + gc] = v;
        }
    }
}

// ---------------- per-node attention-score halves: s_src = z@a[:128], s_dst = z@a[128:] ----------------
__global__ void compute_s(const float* __restrict__ z, const float* __restrict__ a,
                          float* __restrict__ s_src, float* __restrict__ s_dst, int N) {
    const int wave = threadIdx.x >> 6;
    const int lane = threadIdx.x & 63;
    const int n = blockIdx.x * 4 + wave;
    if (n >= N) return;
    const float* zr = z + (long)n * HBLK;
    float v0 = zr[lane], v1 = zr[lane + 64];
    float ss = v0 * a[lane] + v1 * a[lane + 64];
    float sd = v0 * a[128 + lane] + v1 * a[192 + lane];
#pragma unroll
    for (int off = 32; off > 0; off >>= 1) {
        ss += __shfl_down(ss, off);
        sd += __shfl_down(sd, off);
    }
    if (lane == 0) {
        s_src[n] = ss;
        s_dst[n] = sd;
    }
}

// ---------------- GAT edge softmax + aggregation; one block (128 thr) per dst node ----------------
__global__ void gat_agg(const float* __restrict__ h_in, const float* __restrict__ hs,
                        const float* __restrict__ z,
                        const float* __restrict__ s_src, const float* __restrict__ s_dst,
                        const int* __restrict__ offs, const int* __restrict__ src_sorted,
                        float* __restrict__ h_out) {
    const int n = blockIdx.x;
    const int t = threadIdx.x;  // 128
    const int beg = offs[n], end = offs[n + 1];
    const int deg = end - beg;
    const float hin = h_in[(long)n * HBLK + t];
    if (deg == 0) {  // DGL leaves h at h_in; residual doubles it
        h_out[(long)n * HBLK + t] = 2.f * hin;
        return;
    }
    const float sd = s_dst[n];
    __shared__ float red[128];

    // pass 1: max of leaky(e)
    float m = -INFINITY;
    for (int i = beg + t; i < end; i += 128) {
        float e = sd + s_src[src_sorted[i]];
        e = e > 0.f ? e : 0.01f * e;
        m = fmaxf(m, e);
    }
    red[t] = m;
    __syncthreads();
    for (int s2 = 64; s2 > 0; s2 >>= 1) {
        if (t < s2) red[t] = fmaxf(red[t], red[t + s2]);
        __syncthreads();
    }
    m = red[0];
    __syncthreads();

    // pass 2: sum of exp
    float sacc = 0.f;
    for (int i = beg + t; i < end; i += 128) {
        float e = sd + s_src[src_sorted[i]];
        e = e > 0.f ? e : 0.01f * e;
        sacc += __expf(e - m);
    }
    red[t] = sacc;
    __syncthreads();
    for (int s2 = 64; s2 > 0; s2 >>= 1) {
        if (t < s2) red[t] += red[t + s2];
        __syncthreads();
    }
    const float inv = 1.f / fmaxf(red[0], 1e-16f);

    // pass 3: acc = hs + sum alpha * z[src]; each thread owns one column
    float acc = hs[(long)n * HBLK + t];
    for (int i = beg; i < end; ++i) {
        int s = src_sorted[i];               // same addr all threads -> broadcast
        float e = sd + s_src[s];
        e = e > 0.f ? e : 0.01f * e;
        float w = __expf(e - m) * inv;
        acc += w * z[(long)s * HBLK + t];    // 512B coalesced row
    }
    h_out[(long)n * HBLK + t] = hin + acc;
}

// ---------------- output projection: out[N x OUT] = h @ W_out^T + b ----------------
__global__ void out_proj(const float* __restrict__ h, const float* __restrict__ W,
                         const float* __restrict__ b, float* __restrict__ out, int OUTD) {
    __shared__ float hr[HBLK];
    const int n = blockIdx.x;
    const int t = threadIdx.x;  // 128
    hr[t] = h[(long)n * HBLK + t];
    __syncthreads();
    if (t < OUTD) {
        float acc = b[t];
        const float* wr = W + t * HBLK;
#pragma unroll 4
        for (int k = 0; k < HBLK; ++k) acc += hr[k] * wr[k];
        out[(long)n * OUTD + t] = acc;
    }
}

extern "C" void kernel_launch(void* const* d_in, const int* in_sizes, int n_in,
                              void* d_out, int out_size, void* d_ws, size_t ws_size,
                              hipStream_t stream) {
    const float* feats = (const float*)d_in[0];
    // d_in[1] = e_w: unused (W_ee branch dead in reference)
    const float* maps  = (const float*)d_in[2];
    // d_in[3] = snorm_n: unused
    const int* src = (const int*)d_in[4];
    const int* dst = (const int*)d_in[5];
    const float* W_eh  = (const float*)d_in[6];
    const float* b_eh  = (const float*)d_in[7];
    // d_in[8], d_in[9] = W_ee, b_ee: unused
    const float* W_cat = (const float*)d_in[10];
    const float* b_cat = (const float*)d_in[11];
    const float* Ws1 = (const float*)d_in[12];
    const float* Wf1 = (const float*)d_in[13];
    const float* a1  = (const float*)d_in[14];
    const float* Ws2 = (const float*)d_in[15];
    const float* Wf2 = (const float*)d_in[16];
    const float* a2  = (const float*)d_in[17];
    const float* W_out = (const float*)d_in[18];
    const float* b_out = (const float*)d_in[19];

    const int N = in_sizes[3];            // snorm_n is (N,1)
    const int E = in_sizes[4];
    const int IN_DIM = in_sizes[0] / N;   // 24
    const int MAPD = in_sizes[2] / N;     // 512
    const int OUTD = in_sizes[19];        // 24

    // workspace layout (floats)
    float* ws = (float*)d_ws;
    const size_t NH = (size_t)N * HBLK;
    float* h0   = ws;            // N*128, later reused as hs
    float* hin  = h0 + NH;       // N*128
    float* zb   = hin + NH;      // N*128
    float* hout = zb + NH;       // N*128
    float* ssrc = hout + NH;     // N
    float* sdst = ssrc + N;      // N
    int* counts = (int*)(sdst + N);  // N
    int* offs   = counts + N;        // N+1
    int* cursor = offs + N + 1;      // N
    int* srcs   = cursor + N;        // E
    float* hs = h0;

    // ---- CSR by dst (rebuilt every call; ws is poisoned between calls) ----
    zero_counts<<<(N + 255) / 256, 256, 0, stream>>>(counts, N);
    hist_k<<<(E + 255) / 256, 256, 0, stream>>>(dst, counts, E);
    scan_k<<<1, 256, 0, stream>>>(counts, offs, cursor, N);
    fill_k<<<(E + 255) / 256, 256, 0, stream>>>(dst, src, cursor, srcs, E);

    const int gGrid = (N + 31) / 32;
    // ---- embedding front-end ----
    gemm_nt<<<gGrid, 256, 0, stream>>>(feats, IN_DIM, W_eh, IN_DIM, b_eh, h0, N, IN_DIM, 0);
    gemm_nt<<<gGrid, 256, 0, stream>>>(maps, MAPD, W_cat, MAPD + HBLK, b_cat, hin, N, MAPD, 0);
    gemm_nt<<<gGrid, 256, 0, stream>>>(h0, HBLK, W_cat + MAPD, MAPD + HBLK, nullptr, hin, N, HBLK, 1 | 2);

    // ---- GAT layer 1: hin -> hout ----
    gemm_nt<<<gGrid, 256, 0, stream>>>(hin, HBLK, Ws1, HBLK, nullptr, hs, N, HBLK, 0);
    gemm_nt<<<gGrid, 256, 0, stream>>>(hin, HBLK, Wf1, HBLK, nullptr, zb, N, HBLK, 0);
    compute_s<<<(N + 3) / 4, 256, 0, stream>>>(zb, a1, ssrc, sdst, N);
    gat_agg<<<N, 128, 0, stream>>>(hin, hs, zb, ssrc, sdst, offs, srcs, hout);

    // ---- GAT layer 2: hout -> hin ----
    gemm_nt<<<gGrid, 256, 0, stream>>>(hout, HBLK, Ws2, HBLK, nullptr, hs, N, HBLK, 0);
    gemm_nt<<<gGrid, 256, 0, stream>>>(hout, HBLK, Wf2, HBLK, nullptr, zb, N, HBLK, 0);
    compute_s<<<(N + 3) / 4, 256, 0, stream>>>(zb, a2, ssrc, sdst, N);
    gat_agg<<<N, 128, 0, stream>>>(hout, hs, zb, ssrc, sdst, offs, srcs, hin);

    // ---- output projection ----
    out_proj<<<N, 128, 0, stream>>>(hin, W_out, b_out, (float*)d_out, OUTD);
}

// Round 2
// 568.622 us; speedup vs baseline: 1.1416x; 1.1416x over previous
//
#include <hip/hip_runtime.h>

#define HBLK 128  // hidden width, fixed by problem

// ---------------- CSR build ----------------
__global__ void zero_counts(int* counts, int n) {
    int i = blockIdx.x * 256 + threadIdx.x;
    if (i < n) counts[i] = 0;
}

__global__ void hist_k(const int* __restrict__ dst, int* counts, int E) {
    int e = blockIdx.x * 256 + threadIdx.x;
    if (e < E) atomicAdd(&counts[dst[e]], 1);
}

// single-block exclusive scan over N counts -> offsets[N+1], cursor copy
__global__ void scan_k(const int* __restrict__ counts, int* offs, int* cursor, int n) {
    __shared__ int lds[256];
    const int t = threadIdx.x;
    const int CH = (n + 255) / 256;
    const int base = t * CH;
    int s = 0;
    for (int i = 0; i < CH; ++i) {
        int idx = base + i;
        if (idx < n) s += counts[idx];
    }
    lds[t] = s;
    __syncthreads();
    for (int off = 1; off < 256; off <<= 1) {
        int add = (t >= off) ? lds[t - off] : 0;
        __syncthreads();
        lds[t] += add;
        __syncthreads();
    }
    int run = lds[t] - s;  // exclusive prefix
    for (int i = 0; i < CH; ++i) {
        int idx = base + i;
        if (idx < n) {
            offs[idx] = run;
            cursor[idx] = run;
            run += counts[idx];
        }
    }
    if (t == 255) offs[n] = lds[255];
}

__global__ void fill_k(const int* __restrict__ dst, const int* __restrict__ src,
                       int* cursor, int* __restrict__ src_sorted, int E) {
    int e = blockIdx.x * 256 + threadIdx.x;
    if (e < E) {
        int p = atomicAdd(&cursor[dst[e]], 1);
        src_sorted[p] = src[e];
    }
}

// ---------------- fp32 GEMM: C[M x 128] = act(([A1|A2]) @ B^T + bias) ----------------
// A1 has K1 cols (lda1), A2 (optional) has Ktot-K1 cols (lda2). B is 128 x Ktot row-major.
// flags: 2 = relu. All K's are multiples of 4; M need not be multiple of 32 (guarded).
__global__ __launch_bounds__(256) void gemm32(
    const float* __restrict__ A1, int lda1, int K1,
    const float* __restrict__ A2, int lda2, int Ktot,
    const float* __restrict__ B, int ldb,
    const float* __restrict__ bias,
    float* __restrict__ C,
    int M, int flags)
{
    __shared__ float As[32][36];    // k-major; rows 16B-aligned (36*4=144)
    __shared__ float Bs[32][132];   // k-major; rows 16B-aligned (132*4=528)
    const int tid = threadIdx.x;
    const int row0 = blockIdx.x * 32;
    const int tx = tid & 31;   // cols tx*4 .. tx*4+3
    const int ty = tid >> 5;   // rows ty*4 .. ty*4+3
    float acc[4][4] = {};

    for (int kb = 0; kb < Ktot; kb += 32) {
        // stage A: 1 float4 per thread (32 rows x 32 k)
        {
            const int r = tid >> 3, k4 = tid & 7;
            const int gr = row0 + r;
            const int k = kb + k4 * 4;
            float4 v = make_float4(0.f, 0.f, 0.f, 0.f);
            if (gr < M && k < Ktot) {
                v = (k < K1) ? *(const float4*)&A1[(long)gr * lda1 + k]
                             : *(const float4*)&A2[(long)gr * lda2 + (k - K1)];
            }
            As[k4 * 4 + 0][r] = v.x;
            As[k4 * 4 + 1][r] = v.y;
            As[k4 * 4 + 2][r] = v.z;
            As[k4 * 4 + 3][r] = v.w;
        }
        // stage B: 4 float4 per thread (128 cols x 32 k)
#pragma unroll
        for (int rep = 0; rep < 4; ++rep) {
            const int idx = tid + 256 * rep;
            const int c = idx >> 3, k4 = idx & 7;
            const int k = kb + k4 * 4;
            float4 v = make_float4(0.f, 0.f, 0.f, 0.f);
            if (k < Ktot) v = *(const float4*)&B[(long)c * ldb + k];
            Bs[k4 * 4 + 0][c] = v.x;
            Bs[k4 * 4 + 1][c] = v.y;
            Bs[k4 * 4 + 2][c] = v.z;
            Bs[k4 * 4 + 3][c] = v.w;
        }
        __syncthreads();
#pragma unroll
        for (int kk = 0; kk < 32; ++kk) {
            const float4 av = *(const float4*)&As[kk][ty * 4];
            const float4 bv = *(const float4*)&Bs[kk][tx * 4];
            const float aa[4] = {av.x, av.y, av.z, av.w};
            const float bb[4] = {bv.x, bv.y, bv.z, bv.w};
#pragma unroll
            for (int i = 0; i < 4; ++i)
#pragma unroll
                for (int j = 0; j < 4; ++j)
                    acc[i][j] += aa[i] * bb[j];
        }
        __syncthreads();
    }

#pragma unroll
    for (int i = 0; i < 4; ++i) {
        const int gr = row0 + ty * 4 + i;
        if (gr >= M) continue;
        float4 v;
        float* vp = (float*)&v;
#pragma unroll
        for (int j = 0; j < 4; ++j) {
            float x = acc[i][j] + (bias ? bias[tx * 4 + j] : 0.f);
            if (flags & 2) x = fmaxf(x, 0.f);
            vp[j] = x;
        }
        *(float4*)&C[(long)gr * HBLK + tx * 4] = v;
    }
}

// ---------------- dual fp32 GEMM: Cs = A@Bs^T, Cf = A@Bf^T (both 128x128, K=128) ----------------
__global__ __launch_bounds__(512) void gemm_dual(
    const float* __restrict__ A,
    const float* __restrict__ Bw, const float* __restrict__ Bf,
    float* __restrict__ Cs, float* __restrict__ Cf, int M)
{
    __shared__ float As[32][36];
    __shared__ float Bs[32][260];   // 256 cols (Bw|Bf), rows 16B-aligned
    const int tid = threadIdx.x;
    const int row0 = blockIdx.x * 32;
    const int tx = tid & 63;   // cols tx*4 over 256
    const int ty = tid >> 6;   // rows ty*4 over 32
    float acc[4][4] = {};

    for (int kb = 0; kb < HBLK; kb += 32) {
        if (tid < 256) {
            const int r = tid >> 3, k4 = tid & 7;
            const int gr = row0 + r;
            float4 v = make_float4(0.f, 0.f, 0.f, 0.f);
            if (gr < M) v = *(const float4*)&A[(long)gr * HBLK + kb + k4 * 4];
            As[k4 * 4 + 0][r] = v.x;
            As[k4 * 4 + 1][r] = v.y;
            As[k4 * 4 + 2][r] = v.z;
            As[k4 * 4 + 3][r] = v.w;
        }
#pragma unroll
        for (int rep = 0; rep < 4; ++rep) {
            const int idx = tid + 512 * rep;
            const int c = idx >> 3, k4 = idx & 7;   // c: 0..255
            const float* src = (c < 128) ? &Bw[(long)c * HBLK] : &Bf[(long)(c - 128) * HBLK];
            const float4 v = *(const float4*)&src[kb + k4 * 4];
            Bs[k4 * 4 + 0][c] = v.x;
            Bs[k4 * 4 + 1][c] = v.y;
            Bs[k4 * 4 + 2][c] = v.z;
            Bs[k4 * 4 + 3][c] = v.w;
        }
        __syncthreads();
#pragma unroll
        for (int kk = 0; kk < 32; ++kk) {
            const float4 av = *(const float4*)&As[kk][ty * 4];
            const float4 bv = *(const float4*)&Bs[kk][tx * 4];
            const float aa[4] = {av.x, av.y, av.z, av.w};
            const float bb[4] = {bv.x, bv.y, bv.z, bv.w};
#pragma unroll
            for (int i = 0; i < 4; ++i)
#pragma unroll
                for (int j = 0; j < 4; ++j)
                    acc[i][j] += aa[i] * bb[j];
        }
        __syncthreads();
    }

    const int c = tx * 4;
    float* __restrict__ C = (c < 128) ? Cs : Cf;
    const int cc = c & 127;
#pragma unroll
    for (int i = 0; i < 4; ++i) {
        const int gr = row0 + ty * 4 + i;
        if (gr >= M) continue;
        float4 v = make_float4(acc[i][0], acc[i][1], acc[i][2], acc[i][3]);
        *(float4*)&C[(long)gr * HBLK + cc] = v;
    }
}

// ---------------- per-node attention-score halves: s_src = z@a[:128], s_dst = z@a[128:] ----------------
__global__ void compute_s(const float* __restrict__ z, const float* __restrict__ a,
                          float* __restrict__ s_src, float* __restrict__ s_dst, int N) {
    const int wave = threadIdx.x >> 6;
    const int lane = threadIdx.x & 63;
    const int n = blockIdx.x * 4 + wave;
    if (n >= N) return;
    const float* zr = z + (long)n * HBLK;
    float v0 = zr[lane], v1 = zr[lane + 64];
    float ss = v0 * a[lane] + v1 * a[lane + 64];
    float sd = v0 * a[128 + lane] + v1 * a[192 + lane];
#pragma unroll
    for (int off = 32; off > 0; off >>= 1) {
        ss += __shfl_down(ss, off);
        sd += __shfl_down(sd, off);
    }
    if (lane == 0) {
        s_src[n] = ss;
        s_dst[n] = sd;
    }
}

// ---------------- GAT edge softmax + aggregation; one block (128 thr) per dst node ----------------
__global__ void gat_agg(const float* __restrict__ h_in, const float* __restrict__ hs,
                        const float* __restrict__ z,
                        const float* __restrict__ s_src, const float* __restrict__ s_dst,
                        const int* __restrict__ offs, const int* __restrict__ src_sorted,
                        float* __restrict__ h_out) {
    const int n = blockIdx.x;
    const int t = threadIdx.x;  // 128
    const int beg = offs[n], end = offs[n + 1];
    const int deg = end - beg;
    const float hin = h_in[(long)n * HBLK + t];
    if (deg == 0) {  // DGL leaves h at h_in; residual doubles it
        h_out[(long)n * HBLK + t] = 2.f * hin;
        return;
    }
    const float sd = s_dst[n];
    __shared__ float red[128];

    // pass 1: max of leaky(e)
    float m = -INFINITY;
    for (int i = beg + t; i < end; i += 128) {
        float e = sd + s_src[src_sorted[i]];
        e = e > 0.f ? e : 0.01f * e;
        m = fmaxf(m, e);
    }
    red[t] = m;
    __syncthreads();
    for (int s2 = 64; s2 > 0; s2 >>= 1) {
        if (t < s2) red[t] = fmaxf(red[t], red[t + s2]);
        __syncthreads();
    }
    m = red[0];
    __syncthreads();

    // pass 2: sum of exp
    float sacc = 0.f;
    for (int i = beg + t; i < end; i += 128) {
        float e = sd + s_src[src_sorted[i]];
        e = e > 0.f ? e : 0.01f * e;
        sacc += __expf(e - m);
    }
    red[t] = sacc;
    __syncthreads();
    for (int s2 = 64; s2 > 0; s2 >>= 1) {
        if (t < s2) red[t] += red[t + s2];
        __syncthreads();
    }
    const float inv = 1.f / fmaxf(red[0], 1e-16f);

    // pass 3: acc = hs + sum alpha * z[src]; each thread owns one column
    float acc = hs[(long)n * HBLK + t];
    for (int i = beg; i < end; ++i) {
        int s = src_sorted[i];               // same addr all threads -> broadcast
        float e = sd + s_src[s];
        e = e > 0.f ? e : 0.01f * e;
        float w = __expf(e - m) * inv;
        acc += w * z[(long)s * HBLK + t];    // 512B coalesced row
    }
    h_out[(long)n * HBLK + t] = hin + acc;
}

// ---------------- output projection: out[N x OUT] = h @ W_out^T + b ----------------
__global__ void out_proj(const float* __restrict__ h, const float* __restrict__ W,
                         const float* __restrict__ b, float* __restrict__ out, int OUTD) {
    __shared__ float hr[HBLK];
    const int n = blockIdx.x;
    const int t = threadIdx.x;  // 128
    hr[t] = h[(long)n * HBLK + t];
    __syncthreads();
    if (t < OUTD) {
        float acc = b[t];
        const float* wr = W + t * HBLK;
#pragma unroll 4
        for (int k = 0; k < HBLK; ++k) acc += hr[k] * wr[k];
        out[(long)n * OUTD + t] = acc;
    }
}

extern "C" void kernel_launch(void* const* d_in, const int* in_sizes, int n_in,
                              void* d_out, int out_size, void* d_ws, size_t ws_size,
                              hipStream_t stream) {
    const float* feats = (const float*)d_in[0];
    // d_in[1] = e_w: unused (W_ee branch dead in reference)
    const float* maps  = (const float*)d_in[2];
    // d_in[3] = snorm_n: unused
    const int* src = (const int*)d_in[4];
    const int* dst = (const int*)d_in[5];
    const float* W_eh  = (const float*)d_in[6];
    const float* b_eh  = (const float*)d_in[7];
    // d_in[8], d_in[9] = W_ee, b_ee: unused
    const float* W_cat = (const float*)d_in[10];
    const float* b_cat = (const float*)d_in[11];
    const float* Ws1 = (const float*)d_in[12];
    const float* Wf1 = (const float*)d_in[13];
    const float* a1  = (const float*)d_in[14];
    const float* Ws2 = (const float*)d_in[15];
    const float* Wf2 = (const float*)d_in[16];
    const float* a2  = (const float*)d_in[17];
    const float* W_out = (const float*)d_in[18];
    const float* b_out = (const float*)d_in[19];

    const int N = in_sizes[3];            // snorm_n is (N,1)
    const int E = in_sizes[4];
    const int IN_DIM = in_sizes[0] / N;   // 24
    const int MAPD = in_sizes[2] / N;     // 512
    const int OUTD = in_sizes[19];        // 24

    // workspace layout (floats)
    float* ws = (float*)d_ws;
    const size_t NH = (size_t)N * HBLK;
    float* h0   = ws;            // N*128, later reused as hs
    float* hin  = h0 + NH;       // N*128
    float* zb   = hin + NH;      // N*128
    float* hout = zb + NH;       // N*128
    float* ssrc = hout + NH;     // N
    float* sdst = ssrc + N;      // N
    int* counts = (int*)(sdst + N);  // N
    int* offs   = counts + N;        // N+1
    int* cursor = offs + N + 1;      // N
    int* srcs   = cursor + N;        // E
    float* hs = h0;

    // ---- CSR by dst (rebuilt every call; ws is poisoned between calls) ----
    zero_counts<<<(N + 255) / 256, 256, 0, stream>>>(counts, N);
    hist_k<<<(E + 255) / 256, 256, 0, stream>>>(dst, counts, E);
    scan_k<<<1, 256, 0, stream>>>(counts, offs, cursor, N);
    fill_k<<<(E + 255) / 256, 256, 0, stream>>>(dst, src, cursor, srcs, E);

    const int gGrid = (N + 31) / 32;
    // ---- embedding front-end ----
    gemm32<<<gGrid, 256, 0, stream>>>(feats, IN_DIM, IN_DIM, nullptr, 0, IN_DIM,
                                      W_eh, IN_DIM, b_eh, h0, N, 0);
    // fused concat: hin = relu([maps | h0] @ W_cat^T + b_cat)
    gemm32<<<gGrid, 256, 0, stream>>>(maps, MAPD, MAPD, h0, HBLK, MAPD + HBLK,
                                      W_cat, MAPD + HBLK, b_cat, hin, N, 2);

    // ---- GAT layer 1: hin -> hout ----
    gemm_dual<<<gGrid, 512, 0, stream>>>(hin, Ws1, Wf1, hs, zb, N);
    compute_s<<<(N + 3) / 4, 256, 0, stream>>>(zb, a1, ssrc, sdst, N);
    gat_agg<<<N, 128, 0, stream>>>(hin, hs, zb, ssrc, sdst, offs, srcs, hout);

    // ---- GAT layer 2: hout -> hin ----
    gemm_dual<<<gGrid, 512, 0, stream>>>(hout, Ws2, Wf2, hs, zb, N);
    compute_s<<<(N + 3) / 4, 256, 0, stream>>>(zb, a2, ssrc, sdst, N);
    gat_agg<<<N, 128, 0, stream>>>(hout, hs, zb, ssrc, sdst, offs, srcs, hin);

    // ---- output projection ----
    out_proj<<<N, 128, 0, stream>>>(hin, W_out, b_out, (float*)d_out, OUTD);
}